// Round 1
// baseline (610.900 us; speedup 1.0000x reference)
//
#include <hip/hip_runtime.h>
#include <cstdint>
#include <cstddef>

#define N_NODES 100000
#define N_EDGES 1600000
#define IN_DIM  256
#define OUT_DIM 128

// ---------------- GEMM: z = h @ W  (f32, tiled) ----------------
#define GN 64   // nodes per block
#define GK 64   // k-chunk

__global__ __launch_bounds__(256) void gemm_z_k(
    const float* __restrict__ h, const float* __restrict__ W,
    float* __restrict__ z)
{
    __shared__ float lh[GN][GK + 4];
    __shared__ float lw[GK][OUT_DIM];
    const int t  = threadIdx.x;
    const int n0 = blockIdx.x * GN;
    const int tx = t & 15;   // dims 8*tx .. 8*tx+7
    const int ty = t >> 4;   // nodes ty*4 .. ty*4+3

    float acc[4][8];
    #pragma unroll
    for (int j = 0; j < 4; ++j)
        #pragma unroll
        for (int d = 0; d < 8; ++d) acc[j][d] = 0.0f;

    for (int c = 0; c < IN_DIM; c += GK) {
        // stage h tile: GN x GK floats
        #pragma unroll
        for (int p = 0; p < 4; ++p) {
            int idx = p * 256 + t;        // float4 index, 0..1023
            int i = idx >> 4;             // row (16 float4 per 64-float row)
            int j = (idx & 15) * 4;
            float4 v = make_float4(0.f, 0.f, 0.f, 0.f);
            if (n0 + i < N_NODES)
                v = *(const float4*)&h[(size_t)(n0 + i) * IN_DIM + c + j];
            *(float4*)&lh[i][j] = v;
        }
        // stage W chunk: GK x 128 floats
        #pragma unroll
        for (int p = 0; p < 8; ++p) {
            int idx = p * 256 + t;        // float4 index, 0..2047
            int kk = idx >> 5;            // row (32 float4 per 128-float row)
            int j = (idx & 31) * 4;
            *(float4*)&lw[kk][j] = *(const float4*)&W[(size_t)(c + kk) * OUT_DIM + j];
        }
        __syncthreads();

        for (int k = 0; k < GK; ++k) {
            float4 w0 = *(float4*)&lw[k][tx * 8];
            float4 w1 = *(float4*)&lw[k][tx * 8 + 4];
            #pragma unroll
            for (int j = 0; j < 4; ++j) {
                float hv = lh[ty * 4 + j][k];
                acc[j][0] += hv * w0.x; acc[j][1] += hv * w0.y;
                acc[j][2] += hv * w0.z; acc[j][3] += hv * w0.w;
                acc[j][4] += hv * w1.x; acc[j][5] += hv * w1.y;
                acc[j][6] += hv * w1.z; acc[j][7] += hv * w1.w;
            }
        }
        __syncthreads();
    }

    #pragma unroll
    for (int j = 0; j < 4; ++j) {
        int n = n0 + ty * 4 + j;
        if (n < N_NODES) {
            float4 o0 = make_float4(acc[j][0], acc[j][1], acc[j][2], acc[j][3]);
            float4 o1 = make_float4(acc[j][4], acc[j][5], acc[j][6], acc[j][7]);
            *(float4*)&z[(size_t)n * OUT_DIM + tx * 8]     = o0;
            *(float4*)&z[(size_t)n * OUT_DIM + tx * 8 + 4] = o1;
        }
    }
}

// ---------------- el/er: per-node dot with a ----------------
__global__ __launch_bounds__(256) void el_er_k(
    const float* __restrict__ z, const float* __restrict__ a,
    float* __restrict__ el, float* __restrict__ er)
{
    int wid  = (blockIdx.x * blockDim.x + threadIdx.x) >> 6;
    int lane = threadIdx.x & 63;
    if (wid >= N_NODES) return;
    const float* zr = z + (size_t)wid * OUT_DIM;
    float z0 = zr[lane], z1 = zr[64 + lane];
    float pl = z0 * a[lane]       + z1 * a[64 + lane];
    float pr = z0 * a[128 + lane] + z1 * a[192 + lane];
    #pragma unroll
    for (int o = 32; o > 0; o >>= 1) {
        pl += __shfl_xor(pl, o, 64);
        pr += __shfl_xor(pr, o, 64);
    }
    if (lane == 0) { el[wid] = pl; er[wid] = pr; }
}

// ---------------- CSR build ----------------
__global__ void zero_deg_k(int* __restrict__ deg)
{
    int i = blockIdx.x * blockDim.x + threadIdx.x;
    if (i < N_NODES) deg[i] = 0;
}

__global__ void count_deg_k(const int* __restrict__ dst, int* __restrict__ deg)
{
    int e = blockIdx.x * blockDim.x + threadIdx.x;
    if (e < N_EDGES) atomicAdd(&deg[dst[e]], 1);
}

// per-block exclusive scan over 1024 elements
__global__ __launch_bounds__(256) void scan1_k(
    const int* __restrict__ deg, int* __restrict__ offs_part,
    int* __restrict__ partials)
{
    __shared__ int ts[256];
    int t = threadIdx.x;
    int base = blockIdx.x * 1024 + t * 4;
    int d0 = (base + 0 < N_NODES) ? deg[base + 0] : 0;
    int d1 = (base + 1 < N_NODES) ? deg[base + 1] : 0;
    int d2 = (base + 2 < N_NODES) ? deg[base + 2] : 0;
    int d3 = (base + 3 < N_NODES) ? deg[base + 3] : 0;
    int i0 = d0, i1 = i0 + d1, i2 = i1 + d2, i3 = i2 + d3;
    ts[t] = i3;
    __syncthreads();
    for (int o = 1; o < 256; o <<= 1) {
        int v = (t >= o) ? ts[t - o] : 0;
        __syncthreads();
        ts[t] += v;
        __syncthreads();
    }
    int texcl = ts[t] - i3;
    if (base + 0 < N_NODES) offs_part[base + 0] = texcl + i0 - d0;
    if (base + 1 < N_NODES) offs_part[base + 1] = texcl + i1 - d1;
    if (base + 2 < N_NODES) offs_part[base + 2] = texcl + i2 - d2;
    if (base + 3 < N_NODES) offs_part[base + 3] = texcl + i3 - d3;
    if (t == 255) partials[blockIdx.x] = ts[255];
}

#define NB_SCAN ((N_NODES + 1023) / 1024)   // 98

__global__ __launch_bounds__(256) void scan2_k(
    const int* __restrict__ partials, int* __restrict__ pexcl)
{
    __shared__ int ts[256];
    int t = threadIdx.x;
    int v = (t < NB_SCAN) ? partials[t] : 0;
    ts[t] = v;
    __syncthreads();
    for (int o = 1; o < 256; o <<= 1) {
        int x = (t >= o) ? ts[t - o] : 0;
        __syncthreads();
        ts[t] += x;
        __syncthreads();
    }
    pexcl[t] = ts[t] - v;
}

__global__ void scan3_k(const int* __restrict__ offs_part,
                        const int* __restrict__ pexcl,
                        int* __restrict__ offs, int* __restrict__ cursor)
{
    int i = blockIdx.x * blockDim.x + threadIdx.x;
    if (i < N_NODES) {
        int v = offs_part[i] + pexcl[i >> 10];
        offs[i] = v;
        cursor[i] = v;
    }
    if (i == 0) offs[N_NODES] = N_EDGES;
}

__global__ void scatter_k(const int* __restrict__ src, const int* __restrict__ dst,
                          const float* __restrict__ el, const float* __restrict__ er,
                          int* __restrict__ cursor,
                          int* __restrict__ perm_src, float* __restrict__ perm_e)
{
    int e = blockIdx.x * blockDim.x + threadIdx.x;
    if (e >= N_EDGES) return;
    int s = src[e], d = dst[e];
    float v = el[s] + er[d];
    v = (v > 0.0f) ? v : 0.01f * v;        // leaky_relu slope 0.01
    int p = atomicAdd(&cursor[d], 1);
    perm_src[p] = s;
    perm_e[p] = v;
}

// ---------------- per-node softmax + weighted gather ----------------
__global__ __launch_bounds__(256) void node_pass_k(
    const int* __restrict__ offs, const int* __restrict__ perm_src,
    const float* __restrict__ perm_e, const float* __restrict__ z,
    float* __restrict__ out)
{
    int n    = (blockIdx.x * blockDim.x + threadIdx.x) >> 6;
    int lane = threadIdx.x & 63;
    if (n >= N_NODES) return;
    int beg = offs[n], end = offs[n + 1];

    float acc0 = 0.0f, acc1 = 0.0f;
    if (end > beg) {
        // 1: segment max
        float mx = -3.402823466e38f;
        for (int i = beg + lane; i < end; i += 64) mx = fmaxf(mx, perm_e[i]);
        #pragma unroll
        for (int o = 32; o > 0; o >>= 1) mx = fmaxf(mx, __shfl_xor(mx, o, 64));
        // 2: sum of exp
        float s = 0.0f;
        for (int i = beg + lane; i < end; i += 64) s += __expf(perm_e[i] - mx);
        #pragma unroll
        for (int o = 32; o > 0; o >>= 1) s += __shfl_xor(s, o, 64);
        float inv = 1.0f / s;
        // 3: weighted gather of z[src]
        for (int i = beg; i < end; ++i) {
            float w = __expf(perm_e[i] - mx) * inv;   // wave-uniform
            int sidx = perm_src[i];
            const float* zr = z + (size_t)sidx * OUT_DIM;
            acc0 += w * zr[lane];
            acc1 += w * zr[64 + lane];
        }
    }
    out[(size_t)n * OUT_DIM + lane]      = acc0;
    out[(size_t)n * OUT_DIM + 64 + lane] = acc1;
}

// ---------------- launch ----------------
extern "C" void kernel_launch(void* const* d_in, const int* in_sizes, int n_in,
                              void* d_out, int out_size, void* d_ws, size_t ws_size,
                              hipStream_t stream)
{
    (void)in_sizes; (void)n_in; (void)out_size; (void)ws_size;
    const float* h = (const float*)d_in[0];
    const float* W = (const float*)d_in[1];
    const float* a = (const float*)d_in[2];
    const int* src = (const int*)d_in[3];
    const int* dst = (const int*)d_in[4];
    float* out = (float*)d_out;

    char* ws = (char*)d_ws;
    size_t off = 0;
    auto alloc = [&](size_t bytes) -> char* {
        char* p = ws + off;
        off += (bytes + 255) & ~(size_t)255;
        return p;
    };
    float* z         = (float*)alloc((size_t)N_NODES * OUT_DIM * 4);
    float* el        = (float*)alloc((size_t)N_NODES * 4);
    float* er        = (float*)alloc((size_t)N_NODES * 4);
    int*   deg       = (int*)  alloc((size_t)N_NODES * 4);
    int*   offs_part = (int*)  alloc((size_t)N_NODES * 4);
    int*   offs      = (int*)  alloc((size_t)(N_NODES + 1) * 4);
    int*   cursor    = (int*)  alloc((size_t)N_NODES * 4);
    int*   perm_src  = (int*)  alloc((size_t)N_EDGES * 4);
    float* perm_e    = (float*)alloc((size_t)N_EDGES * 4);
    int*   partials  = (int*)  alloc(256 * 4);
    int*   pexcl     = (int*)  alloc(256 * 4);

    // z = h @ W
    gemm_z_k<<<(N_NODES + GN - 1) / GN, 256, 0, stream>>>(h, W, z);
    // el/er
    el_er_k<<<(N_NODES * 64 + 255) / 256, 256, 0, stream>>>(z, a, el, er);
    // CSR build
    zero_deg_k<<<(N_NODES + 255) / 256, 256, 0, stream>>>(deg);
    count_deg_k<<<(N_EDGES + 255) / 256, 256, 0, stream>>>(dst, deg);
    scan1_k<<<NB_SCAN, 256, 0, stream>>>(deg, offs_part, partials);
    scan2_k<<<1, 256, 0, stream>>>(partials, pexcl);
    scan3_k<<<(N_NODES + 255) / 256, 256, 0, stream>>>(offs_part, pexcl, offs, cursor);
    scatter_k<<<(N_EDGES + 255) / 256, 256, 0, stream>>>(src, dst, el, er, cursor,
                                                         perm_src, perm_e);
    // softmax + gather
    node_pass_k<<<(N_NODES * 64 + 255) / 256, 256, 0, stream>>>(offs, perm_src,
                                                                perm_e, z, out);
}

// Round 2
// 527.805 us; speedup vs baseline: 1.1574x; 1.1574x over previous
//
#include <hip/hip_runtime.h>
#include <cstdint>
#include <cstddef>

#define N_NODES 100000
#define N_EDGES 1600000
#define IN_DIM  256
#define OUT_DIM 128
#define EDGE_CAP 1900032   // N_EDGES + 3*N_NODES, padded-CSR capacity
#define ENC_NEG_INF 0x00800000u   // encode(-FLT_MAX)

__device__ __forceinline__ unsigned bf16rn(float f) {
    unsigned u = __float_as_uint(f);
    return (u + 0x7FFFu + ((u >> 16) & 1u)) >> 16;
}

// ---------------- init: degrees, emax, perm pads ----------------
__global__ void init_k(int* __restrict__ deg, unsigned* __restrict__ emax,
                       int* __restrict__ perm_src, float* __restrict__ perm_e)
{
    int i = blockIdx.x * blockDim.x + threadIdx.x;
    if (i < N_NODES) { deg[i] = 0; emax[i] = ENC_NEG_INF; }
    if (i < EDGE_CAP) { perm_src[i] = 0; perm_e[i] = -3.402823466e38f; }
}

// ---------------- GEMM: z16 = bf16(h @ W), el/er fused epilogue ----------------
#define GN 64
#define GK 64

__global__ __launch_bounds__(256) void gemm_z_k(
    const float* __restrict__ h, const float* __restrict__ W,
    const float* __restrict__ a,
    unsigned* __restrict__ z16, float* __restrict__ el, float* __restrict__ er)
{
    __shared__ float lh[GN][GK + 4];
    __shared__ float lw[GK][OUT_DIM];
    const int t  = threadIdx.x;
    const int n0 = blockIdx.x * GN;
    const int tx = t & 15;   // dims 8*tx .. 8*tx+7
    const int ty = t >> 4;   // nodes ty*4 .. ty*4+3

    float acc[4][8];
    #pragma unroll
    for (int j = 0; j < 4; ++j)
        #pragma unroll
        for (int d = 0; d < 8; ++d) acc[j][d] = 0.0f;

    for (int c = 0; c < IN_DIM; c += GK) {
        #pragma unroll
        for (int p = 0; p < 4; ++p) {
            int idx = p * 256 + t;
            int i = idx >> 4;
            int j = (idx & 15) * 4;
            float4 v = make_float4(0.f, 0.f, 0.f, 0.f);
            if (n0 + i < N_NODES)
                v = *(const float4*)&h[(size_t)(n0 + i) * IN_DIM + c + j];
            *(float4*)&lh[i][j] = v;
        }
        #pragma unroll
        for (int p = 0; p < 8; ++p) {
            int idx = p * 256 + t;
            int kk = idx >> 5;
            int j = (idx & 31) * 4;
            *(float4*)&lw[kk][j] = *(const float4*)&W[(size_t)(c + kk) * OUT_DIM + j];
        }
        __syncthreads();

        for (int k = 0; k < GK; ++k) {
            float4 w0 = *(float4*)&lw[k][tx * 8];
            float4 w1 = *(float4*)&lw[k][tx * 8 + 4];
            #pragma unroll
            for (int j = 0; j < 4; ++j) {
                float hv = lh[ty * 4 + j][k];
                acc[j][0] += hv * w0.x; acc[j][1] += hv * w0.y;
                acc[j][2] += hv * w0.z; acc[j][3] += hv * w0.w;
                acc[j][4] += hv * w1.x; acc[j][5] += hv * w1.y;
                acc[j][6] += hv * w1.z; acc[j][7] += hv * w1.w;
            }
        }
        __syncthreads();
    }

    // epilogue: el/er shuffle-reduce + bf16 z pack
    const float4* a4 = (const float4*)a;
    float4 av0 = a4[tx * 2],      av1 = a4[tx * 2 + 1];
    float4 av2 = a4[32 + tx * 2], av3 = a4[32 + tx * 2 + 1];
    #pragma unroll
    for (int j = 0; j < 4; ++j) {
        int n = n0 + ty * 4 + j;
        float sl = acc[j][0]*av0.x + acc[j][1]*av0.y + acc[j][2]*av0.z + acc[j][3]*av0.w
                 + acc[j][4]*av1.x + acc[j][5]*av1.y + acc[j][6]*av1.z + acc[j][7]*av1.w;
        float sr = acc[j][0]*av2.x + acc[j][1]*av2.y + acc[j][2]*av2.z + acc[j][3]*av2.w
                 + acc[j][4]*av3.x + acc[j][5]*av3.y + acc[j][6]*av3.z + acc[j][7]*av3.w;
        #pragma unroll
        for (int o = 1; o < 16; o <<= 1) {
            sl += __shfl_xor(sl, o, 64);
            sr += __shfl_xor(sr, o, 64);
        }
        uint4 pk;
        pk.x = bf16rn(acc[j][0]) | (bf16rn(acc[j][1]) << 16);
        pk.y = bf16rn(acc[j][2]) | (bf16rn(acc[j][3]) << 16);
        pk.z = bf16rn(acc[j][4]) | (bf16rn(acc[j][5]) << 16);
        pk.w = bf16rn(acc[j][6]) | (bf16rn(acc[j][7]) << 16);
        if (n < N_NODES) {
            *(uint4*)&z16[(size_t)n * 64 + tx * 4] = pk;
            if (tx == 0) { el[n] = sl; er[n] = sr; }
        }
    }
}

// ---------------- CSR build (padded to multiples of 4) ----------------
__global__ void count_deg_k(const int* __restrict__ dst, int* __restrict__ deg)
{
    int e = blockIdx.x * blockDim.x + threadIdx.x;
    if (e < N_EDGES) atomicAdd(&deg[dst[e]], 1);
}

__global__ __launch_bounds__(256) void scan1_k(
    const int* __restrict__ deg, int* __restrict__ offs_part,
    int* __restrict__ partials)
{
    __shared__ int ts[256];
    int t = threadIdx.x;
    int base = blockIdx.x * 1024 + t * 4;
    int d0 = (base + 0 < N_NODES) ? deg[base + 0] : 0;
    int d1 = (base + 1 < N_NODES) ? deg[base + 1] : 0;
    int d2 = (base + 2 < N_NODES) ? deg[base + 2] : 0;
    int d3 = (base + 3 < N_NODES) ? deg[base + 3] : 0;
    int p0 = (d0 + 3) & ~3, p1 = (d1 + 3) & ~3;
    int p2 = (d2 + 3) & ~3, p3 = (d3 + 3) & ~3;
    int i0 = p0, i1 = i0 + p1, i2 = i1 + p2, i3 = i2 + p3;
    ts[t] = i3;
    __syncthreads();
    for (int o = 1; o < 256; o <<= 1) {
        int v = (t >= o) ? ts[t - o] : 0;
        __syncthreads();
        ts[t] += v;
        __syncthreads();
    }
    int texcl = ts[t] - i3;
    if (base + 0 < N_NODES) offs_part[base + 0] = texcl + i0 - p0;
    if (base + 1 < N_NODES) offs_part[base + 1] = texcl + i1 - p1;
    if (base + 2 < N_NODES) offs_part[base + 2] = texcl + i2 - p2;
    if (base + 3 < N_NODES) offs_part[base + 3] = texcl + i3 - p3;
    if (t == 255) partials[blockIdx.x] = ts[255];
}

#define NB_SCAN ((N_NODES + 1023) / 1024)   // 98

__global__ __launch_bounds__(256) void scan2_k(
    const int* __restrict__ partials, int* __restrict__ pexcl,
    int* __restrict__ offs)
{
    __shared__ int ts[256];
    int t = threadIdx.x;
    int v = (t < NB_SCAN) ? partials[t] : 0;
    ts[t] = v;
    __syncthreads();
    for (int o = 1; o < 256; o <<= 1) {
        int x = (t >= o) ? ts[t - o] : 0;
        __syncthreads();
        ts[t] += x;
        __syncthreads();
    }
    pexcl[t] = ts[t] - v;
    if (t == 255) offs[N_NODES] = ts[255];   // total padded edge count
}

__global__ void scan3_k(const int* __restrict__ offs_part,
                        const int* __restrict__ pexcl,
                        int* __restrict__ offs, int* __restrict__ cursor)
{
    int i = blockIdx.x * blockDim.x + threadIdx.x;
    if (i < N_NODES) {
        int v = offs_part[i] + pexcl[i >> 10];
        offs[i] = v;
        cursor[i] = v;
    }
}

__global__ void scatter_k(const int* __restrict__ src, const int* __restrict__ dst,
                          const float* __restrict__ el, const float* __restrict__ er,
                          int* __restrict__ cursor, unsigned* __restrict__ emax,
                          int* __restrict__ perm_src, float* __restrict__ perm_e)
{
    int e = blockIdx.x * blockDim.x + threadIdx.x;
    if (e >= N_EDGES) return;
    int s = src[e], d = dst[e];
    float v = el[s] + er[d];
    v = (v > 0.0f) ? v : 0.01f * v;        // leaky_relu slope 0.01
    unsigned b = __float_as_uint(v);
    unsigned enc = (b & 0x80000000u) ? ~b : (b | 0x80000000u);
    atomicMax(&emax[d], enc);
    int p = atomicAdd(&cursor[d], 1);
    perm_src[p] = s;
    perm_e[p] = v;
}

// ---------------- fused softmax + weighted gather (single loop) ----------------
__global__ __launch_bounds__(256) void node_pass_k(
    const int* __restrict__ offs, const unsigned* __restrict__ emax,
    const int* __restrict__ perm_src, const float* __restrict__ perm_e,
    const unsigned* __restrict__ z16, float* __restrict__ out)
{
    int n    = (blockIdx.x * blockDim.x + threadIdx.x) >> 6;
    int lane = threadIdx.x & 63;
    if (n >= N_NODES) return;
    int beg = offs[n], end = offs[n + 1];

    float acc0 = 0.0f, acc1 = 0.0f;
    if (end > beg) {
        unsigned u = emax[n];
        float mx = (u & 0x80000000u) ? __uint_as_float(u ^ 0x80000000u)
                                     : __uint_as_float(~u);
        float denom = 0.0f;
        const int4*   ps4 = (const int4*)perm_src;
        const float4* pe4 = (const float4*)perm_e;
        #pragma unroll 2
        for (int i = (beg >> 2); i < (end >> 2); ++i) {
            int4   s = ps4[i];
            float4 e = pe4[i];
            unsigned q0 = z16[(size_t)s.x * 64 + lane];
            unsigned q1 = z16[(size_t)s.y * 64 + lane];
            unsigned q2 = z16[(size_t)s.z * 64 + lane];
            unsigned q3 = z16[(size_t)s.w * 64 + lane];
            float w0 = __expf(e.x - mx), w1 = __expf(e.y - mx);
            float w2 = __expf(e.z - mx), w3 = __expf(e.w - mx);
            denom += (w0 + w1) + (w2 + w3);
            acc0 += w0 * __uint_as_float(q0 << 16)
                  + w1 * __uint_as_float(q1 << 16)
                  + w2 * __uint_as_float(q2 << 16)
                  + w3 * __uint_as_float(q3 << 16);
            acc1 += w0 * __uint_as_float(q0 & 0xFFFF0000u)
                  + w1 * __uint_as_float(q1 & 0xFFFF0000u)
                  + w2 * __uint_as_float(q2 & 0xFFFF0000u)
                  + w3 * __uint_as_float(q3 & 0xFFFF0000u);
        }
        float inv = 1.0f / denom;
        acc0 *= inv; acc1 *= inv;
    }
    *(float2*)&out[(size_t)n * OUT_DIM + lane * 2] = make_float2(acc0, acc1);
}

// ---------------- launch ----------------
extern "C" void kernel_launch(void* const* d_in, const int* in_sizes, int n_in,
                              void* d_out, int out_size, void* d_ws, size_t ws_size,
                              hipStream_t stream)
{
    (void)in_sizes; (void)n_in; (void)out_size; (void)ws_size;
    const float* h = (const float*)d_in[0];
    const float* W = (const float*)d_in[1];
    const float* a = (const float*)d_in[2];
    const int* src = (const int*)d_in[3];
    const int* dst = (const int*)d_in[4];
    float* out = (float*)d_out;

    char* ws = (char*)d_ws;
    size_t off = 0;
    auto alloc = [&](size_t bytes) -> char* {
        char* p = ws + off;
        off += (bytes + 255) & ~(size_t)255;
        return p;
    };
    unsigned* z16      = (unsigned*)alloc((size_t)N_NODES * 64 * 4);   // bf16x2
    float*    el       = (float*)   alloc((size_t)N_NODES * 4);
    float*    er       = (float*)   alloc((size_t)N_NODES * 4);
    int*      deg      = (int*)     alloc((size_t)N_NODES * 4);
    int*      offs_part= (int*)     alloc((size_t)N_NODES * 4);
    int*      offs     = (int*)     alloc((size_t)(N_NODES + 1) * 4);
    int*      cursor   = (int*)     alloc((size_t)N_NODES * 4);
    unsigned* emax     = (unsigned*)alloc((size_t)N_NODES * 4);
    int*      perm_src = (int*)     alloc((size_t)EDGE_CAP * 4);
    float*    perm_e   = (float*)   alloc((size_t)EDGE_CAP * 4);
    int*      partials = (int*)     alloc(256 * 4);
    int*      pexcl    = (int*)     alloc(256 * 4);

    init_k<<<(EDGE_CAP + 255) / 256, 256, 0, stream>>>(deg, emax, perm_src, perm_e);
    gemm_z_k<<<(N_NODES + GN - 1) / GN, 256, 0, stream>>>(h, W, a, z16, el, er);
    count_deg_k<<<(N_EDGES + 255) / 256, 256, 0, stream>>>(dst, deg);
    scan1_k<<<NB_SCAN, 256, 0, stream>>>(deg, offs_part, partials);
    scan2_k<<<1, 256, 0, stream>>>(partials, pexcl, offs);
    scan3_k<<<(N_NODES + 255) / 256, 256, 0, stream>>>(offs_part, pexcl, offs, cursor);
    scatter_k<<<(N_EDGES + 255) / 256, 256, 0, stream>>>(src, dst, el, er, cursor,
                                                         emax, perm_src, perm_e);
    node_pass_k<<<(N_NODES * 64 + 255) / 256, 256, 0, stream>>>(offs, emax, perm_src,
                                                                perm_e, z16, out);
}

// Round 4
// 477.225 us; speedup vs baseline: 1.2801x; 1.1060x over previous
//
#include <hip/hip_runtime.h>
#include <cstdint>
#include <cstddef>

#define N_NODES 100000
#define N_EDGES 1600000
#define IN_DIM  256
#define OUT_DIM 128
#define EDGE_CAP 1900032   // N_EDGES + 3*N_NODES, padded-CSR capacity
#define ENC_NEG_INF 0x00800000u          // encode(-FLT_MAX)
#define PAD_PAIR 0xFF7FFFFF00000000ull   // (e=-FLT_MAX, src=0)

typedef __attribute__((ext_vector_type(8))) short bf16x8;
typedef __attribute__((ext_vector_type(4))) float f32x4;

__device__ __forceinline__ unsigned bf16rn(float f) {
    unsigned u = __float_as_uint(f);
    return (u + 0x7FFFu + ((u >> 16) & 1u)) >> 16;
}

// ---------------- init ----------------
__global__ void init_k(int* __restrict__ deg, unsigned* __restrict__ emax,
                       unsigned long long* __restrict__ perm)
{
    int i = blockIdx.x * blockDim.x + threadIdx.x;
    if (i < N_NODES) { deg[i] = 0; emax[i] = ENC_NEG_INF; }
    if (i < EDGE_CAP) perm[i] = PAD_PAIR;
}

// ---------------- W -> bf16, swizzled to B-fragment order ----------------
// w16s[(((kc*8 + c)*4 + q)*16 + n)*8 + j] = bf16(W[(kc*32+q*8+j)*128 + c*16+n])
__global__ void w16s_k(const float* __restrict__ W, unsigned short* __restrict__ w16s)
{
    int t = blockIdx.x * blockDim.x + threadIdx.x;   // 32768 threads
    if (t >= IN_DIM * OUT_DIM) return;
    int j  = t & 7;
    int n  = (t >> 3) & 15;
    int q  = (t >> 7) & 3;
    int c  = (t >> 9) & 7;
    int kc = t >> 12;
    int k   = kc * 32 + q * 8 + j;
    int dim = c * 16 + n;
    w16s[t] = (unsigned short)bf16rn(W[k * OUT_DIM + dim]);
}

// ---------------- MFMA GEMM: z16 = bf16(h @ W), el/er fused ----------------
// block: 256 thr = 4 waves; 64 nodes/block; each wave 16 nodes x 128 dims.
#define LA_STRIDE 264   // bf16 elems per LDS row (16B-aligned, breaks pow2 stride)

__global__ __launch_bounds__(256) void gemm_z_k(
    const float* __restrict__ h, const unsigned short* __restrict__ w16s,
    const float* __restrict__ a,
    unsigned short* __restrict__ z16, float* __restrict__ el, float* __restrict__ er)
{
    __shared__ unsigned short lA[64 * LA_STRIDE];
    const int t  = threadIdx.x;
    const int n0 = blockIdx.x * 64;

    // stage h tile (64 nodes x 256 k), f32 -> bf16
    #pragma unroll
    for (int p = 0; p < 16; ++p) {
        int f = p * 256 + t;          // float4 index in 64x256 tile
        int i = f >> 6;               // node row
        int col = (f & 63) * 4;       // k col
        float4 v = make_float4(0.f, 0.f, 0.f, 0.f);
        if (n0 + i < N_NODES)
            v = *(const float4*)&h[(size_t)(n0 + i) * IN_DIM + col];
        uint2 pk;
        pk.x = bf16rn(v.x) | (bf16rn(v.y) << 16);
        pk.y = bf16rn(v.z) | (bf16rn(v.w) << 16);
        *(uint2*)&lA[i * LA_STRIDE + col] = pk;
    }
    __syncthreads();

    const int w    = t >> 6;
    const int lane = t & 63;
    const int q    = lane >> 4;
    const int col  = lane & 15;

    f32x4 acc[8];
    #pragma unroll
    for (int c = 0; c < 8; ++c) acc[c] = (f32x4){0.f, 0.f, 0.f, 0.f};

    #pragma unroll
    for (int kc = 0; kc < 8; ++kc) {
        bf16x8 af = *(const bf16x8*)&lA[(w * 16 + col) * LA_STRIDE + kc * 32 + q * 8];
        bf16x8 bfr[8];
        #pragma unroll
        for (int c = 0; c < 8; ++c)
            bfr[c] = *(const bf16x8*)&w16s[((((kc * 8 + c) * 4 + q) * 16) + col) * 8];
        #pragma unroll
        for (int c = 0; c < 8; ++c)
            acc[c] = __builtin_amdgcn_mfma_f32_16x16x32_bf16(af, bfr[c], acc[c], 0, 0, 0);
    }

    // epilogue: el/er + z16 pack.  D layout: node = w*16 + q*4 + r, dim = c*16 + col
    float aL[8], aR[8];
    #pragma unroll
    for (int c = 0; c < 8; ++c) {
        aL[c] = a[c * 16 + col];
        aR[c] = a[128 + c * 16 + col];
    }
    #pragma unroll
    for (int r = 0; r < 4; ++r) {
        int node = n0 + w * 16 + q * 4 + r;
        float sl = 0.f, sr = 0.f;
        #pragma unroll
        for (int c = 0; c < 8; ++c) {
            sl += acc[c][r] * aL[c];
            sr += acc[c][r] * aR[c];
        }
        #pragma unroll
        for (int o = 1; o < 16; o <<= 1) {
            sl += __shfl_xor(sl, o, 64);
            sr += __shfl_xor(sr, o, 64);
        }
        if (node < N_NODES) {
            #pragma unroll
            for (int c = 0; c < 8; ++c)
                z16[(size_t)node * OUT_DIM + c * 16 + col] =
                    (unsigned short)bf16rn(acc[c][r]);
            if (col == 0) { el[node] = sl; er[node] = sr; }
        }
    }
}

// ---------------- CSR build (padded to multiples of 4) ----------------
__global__ void count_deg_k(const int* __restrict__ dst, int* __restrict__ deg)
{
    int tid = blockIdx.x * blockDim.x + threadIdx.x;
    if (tid >= N_EDGES / 4) return;
    int4 d4 = ((const int4*)dst)[tid];
    atomicAdd(&deg[d4.x], 1);
    atomicAdd(&deg[d4.y], 1);
    atomicAdd(&deg[d4.z], 1);
    atomicAdd(&deg[d4.w], 1);
}

__global__ __launch_bounds__(256) void scan1_k(
    const int* __restrict__ deg, int* __restrict__ offs_part,
    int* __restrict__ partials)
{
    __shared__ int ts[256];
    int t = threadIdx.x;
    int base = blockIdx.x * 1024 + t * 4;
    int d0 = (base + 0 < N_NODES) ? deg[base + 0] : 0;
    int d1 = (base + 1 < N_NODES) ? deg[base + 1] : 0;
    int d2 = (base + 2 < N_NODES) ? deg[base + 2] : 0;
    int d3 = (base + 3 < N_NODES) ? deg[base + 3] : 0;
    int p0 = (d0 + 3) & ~3, p1 = (d1 + 3) & ~3;
    int p2 = (d2 + 3) & ~3, p3 = (d3 + 3) & ~3;
    int i0 = p0, i1 = i0 + p1, i2 = i1 + p2, i3 = i2 + p3;
    ts[t] = i3;
    __syncthreads();
    for (int o = 1; o < 256; o <<= 1) {
        int v = (t >= o) ? ts[t - o] : 0;
        __syncthreads();
        ts[t] += v;
        __syncthreads();
    }
    int texcl = ts[t] - i3;
    if (base + 0 < N_NODES) offs_part[base + 0] = texcl + i0 - p0;
    if (base + 1 < N_NODES) offs_part[base + 1] = texcl + i1 - p1;
    if (base + 2 < N_NODES) offs_part[base + 2] = texcl + i2 - p2;
    if (base + 3 < N_NODES) offs_part[base + 3] = texcl + i3 - p3;
    if (t == 255) partials[blockIdx.x] = ts[255];
}

#define NB_SCAN ((N_NODES + 1023) / 1024)   // 98

__global__ __launch_bounds__(256) void scan2_k(
    const int* __restrict__ partials, int* __restrict__ pexcl,
    int* __restrict__ offs)
{
    __shared__ int ts[256];
    int t = threadIdx.x;
    int v = (t < NB_SCAN) ? partials[t] : 0;
    ts[t] = v;
    __syncthreads();
    for (int o = 1; o < 256; o <<= 1) {
        int x = (t >= o) ? ts[t - o] : 0;
        __syncthreads();
        ts[t] += x;
        __syncthreads();
    }
    pexcl[t] = ts[t] - v;
    if (t == 255) offs[N_NODES] = ts[255];
}

__global__ void scan3_k(const int* __restrict__ offs_part,
                        const int* __restrict__ pexcl,
                        int* __restrict__ offs, int* __restrict__ cursor)
{
    int i = blockIdx.x * blockDim.x + threadIdx.x;
    if (i < N_NODES) {
        int v = offs_part[i] + pexcl[i >> 10];
        offs[i] = v;
        cursor[i] = v;
    }
}

// ---------------- scatter: 4 edges/thread, paired 8B stores ----------------
__global__ void scatter_k(const int* __restrict__ src, const int* __restrict__ dst,
                          const float* __restrict__ el, const float* __restrict__ er,
                          int* __restrict__ cursor, unsigned* __restrict__ emax,
                          unsigned long long* __restrict__ perm)
{
    int tid = blockIdx.x * blockDim.x + threadIdx.x;
    if (tid >= N_EDGES / 4) return;
    int4 s4 = ((const int4*)src)[tid];
    int4 d4 = ((const int4*)dst)[tid];
    int ss[4] = {s4.x, s4.y, s4.z, s4.w};
    int dd[4] = {d4.x, d4.y, d4.z, d4.w};
    float vv[4];
    #pragma unroll
    for (int i = 0; i < 4; ++i) {
        float v = el[ss[i]] + er[dd[i]];
        v = (v > 0.0f) ? v : 0.01f * v;   // leaky_relu slope 0.01
        vv[i] = v;
        unsigned b = __float_as_uint(v);
        unsigned enc = (b & 0x80000000u) ? ~b : (b | 0x80000000u);
        atomicMax(&emax[dd[i]], enc);     // fire-and-forget
    }
    int pp[4];
    #pragma unroll
    for (int i = 0; i < 4; ++i) pp[i] = atomicAdd(&cursor[dd[i]], 1);
    #pragma unroll
    for (int i = 0; i < 4; ++i)
        perm[pp[i]] = ((unsigned long long)__float_as_uint(vv[i]) << 32)
                    | (unsigned)ss[i];
}

// ---------------- fused softmax + weighted gather ----------------
__global__ __launch_bounds__(256) void node_pass_k(
    const int* __restrict__ offs, const unsigned* __restrict__ emax,
    const unsigned long long* __restrict__ perm,
    const unsigned* __restrict__ z16, float* __restrict__ out)
{
    int n    = (blockIdx.x * blockDim.x + threadIdx.x) >> 6;
    int lane = threadIdx.x & 63;
    if (n >= N_NODES) return;
    int beg = offs[n], end = offs[n + 1];

    float acc0 = 0.0f, acc1 = 0.0f;
    if (end > beg) {
        unsigned u = emax[n];
        float mx = (u & 0x80000000u) ? __uint_as_float(u ^ 0x80000000u)
                                     : __uint_as_float(~u);
        float denom = 0.0f;
        const uint4* pp = (const uint4*)perm;   // {src0,e0,src1,e1}
        #pragma unroll 2
        for (int i = (beg >> 2); i < (end >> 2); ++i) {
            uint4 pA = pp[2 * i];
            uint4 pB = pp[2 * i + 1];
            unsigned q0 = z16[(size_t)pA.x * 64 + lane];
            unsigned q1 = z16[(size_t)pA.z * 64 + lane];
            unsigned q2 = z16[(size_t)pB.x * 64 + lane];
            unsigned q3 = z16[(size_t)pB.z * 64 + lane];
            float w0 = __expf(__uint_as_float(pA.y) - mx);
            float w1 = __expf(__uint_as_float(pA.w) - mx);
            float w2 = __expf(__uint_as_float(pB.y) - mx);
            float w3 = __expf(__uint_as_float(pB.w) - mx);
            denom += (w0 + w1) + (w2 + w3);
            acc0 += w0 * __uint_as_float(q0 << 16)
                  + w1 * __uint_as_float(q1 << 16)
                  + w2 * __uint_as_float(q2 << 16)
                  + w3 * __uint_as_float(q3 << 16);
            acc1 += w0 * __uint_as_float(q0 & 0xFFFF0000u)
                  + w1 * __uint_as_float(q1 & 0xFFFF0000u)
                  + w2 * __uint_as_float(q2 & 0xFFFF0000u)
                  + w3 * __uint_as_float(q3 & 0xFFFF0000u);
        }
        float inv = 1.0f / denom;
        acc0 *= inv; acc1 *= inv;
    }
    *(float2*)&out[(size_t)n * OUT_DIM + lane * 2] = make_float2(acc0, acc1);
}

// ---------------- launch ----------------
extern "C" void kernel_launch(void* const* d_in, const int* in_sizes, int n_in,
                              void* d_out, int out_size, void* d_ws, size_t ws_size,
                              hipStream_t stream)
{
    (void)in_sizes; (void)n_in; (void)out_size; (void)ws_size;
    const float* h = (const float*)d_in[0];
    const float* W = (const float*)d_in[1];
    const float* a = (const float*)d_in[2];
    const int* src = (const int*)d_in[3];
    const int* dst = (const int*)d_in[4];
    float* out = (float*)d_out;

    char* ws = (char*)d_ws;
    size_t off = 0;
    auto alloc = [&](size_t bytes) -> char* {
        char* p = ws + off;
        off += (bytes + 255) & ~(size_t)255;
        return p;
    };
    unsigned short* z16  = (unsigned short*)alloc((size_t)N_NODES * OUT_DIM * 2);
    unsigned short* w16s = (unsigned short*)alloc((size_t)IN_DIM * OUT_DIM * 2);
    float*    el        = (float*)   alloc((size_t)N_NODES * 4);
    float*    er        = (float*)   alloc((size_t)N_NODES * 4);
    int*      deg       = (int*)     alloc((size_t)N_NODES * 4);
    int*      offs_part = (int*)     alloc((size_t)N_NODES * 4);
    int*      offs      = (int*)     alloc((size_t)(N_NODES + 1) * 4);
    int*      cursor    = (int*)     alloc((size_t)N_NODES * 4);
    unsigned* emax      = (unsigned*)alloc((size_t)N_NODES * 4);
    unsigned long long* perm = (unsigned long long*)alloc((size_t)EDGE_CAP * 8);
    int*      partials  = (int*)     alloc(256 * 4);
    int*      pexcl     = (int*)     alloc(256 * 4);

    init_k<<<(EDGE_CAP + 255) / 256, 256, 0, stream>>>(deg, emax, perm);
    w16s_k<<<(IN_DIM * OUT_DIM + 255) / 256, 256, 0, stream>>>(W, w16s);
    gemm_z_k<<<(N_NODES + 63) / 64, 256, 0, stream>>>(h, w16s, a, z16, el, er);
    count_deg_k<<<(N_EDGES / 4 + 255) / 256, 256, 0, stream>>>(dst, deg);
    scan1_k<<<NB_SCAN, 256, 0, stream>>>(deg, offs_part, partials);
    scan2_k<<<1, 256, 0, stream>>>(partials, pexcl, offs);
    scan3_k<<<(N_NODES + 255) / 256, 256, 0, stream>>>(offs_part, pexcl, offs, cursor);
    scatter_k<<<(N_EDGES / 4 + 255) / 256, 256, 0, stream>>>(src, dst, el, er,
                                                             cursor, emax, perm);
    node_pass_k<<<(N_NODES * 64 + 255) / 256, 256, 0, stream>>>(offs, emax, perm,
                                                                (const unsigned*)z16, out);
}

// Round 5
// 309.765 us; speedup vs baseline: 1.9721x; 1.5406x over previous
//
#include <hip/hip_runtime.h>
#include <cstdint>
#include <cstddef>

#define N_NODES 100000
#define N_EDGES 1600000
#define IN_DIM  256
#define OUT_DIM 128

#define NBUCK  196       // ceil(N_NODES / 512)
#define BSHIFT 9
#define BNODES 512       // nodes per bucket
#define BCAP   10240     // slots per bucket (mean padded ~8960, >12 sigma headroom)
#define EPB    4096      // edges per partition block

#define ENC_NEG_INF 0x00800000u          // encode(-FLT_MAX)
#define PAD_PAIR 0xFF7FFFFF00000000ull   // (e=-FLT_MAX, src=0)

typedef __attribute__((ext_vector_type(8))) short bf16x8;
typedef __attribute__((ext_vector_type(4))) float f32x4;

__device__ __forceinline__ unsigned bf16rn(float f) {
    unsigned u = __float_as_uint(f);
    return (u + 0x7FFFu + ((u >> 16) & 1u)) >> 16;
}

// ---------------- init: zero bucket cursors ----------------
__global__ void init_k(int* __restrict__ bucket_cursor)
{
    int t = threadIdx.x;
    if (t < NBUCK) bucket_cursor[t] = 0;
}

// ---------------- W -> bf16, swizzled to B-fragment order ----------------
__global__ void w16s_k(const float* __restrict__ W, unsigned short* __restrict__ w16s)
{
    int t = blockIdx.x * blockDim.x + threadIdx.x;
    if (t >= IN_DIM * OUT_DIM) return;
    int j  = t & 7;
    int n  = (t >> 3) & 15;
    int q  = (t >> 7) & 3;
    int c  = (t >> 9) & 7;
    int kc = t >> 12;
    int k   = kc * 32 + q * 8 + j;
    int dim = c * 16 + n;
    w16s[t] = (unsigned short)bf16rn(W[k * OUT_DIM + dim]);
}

// ---------------- MFMA GEMM: z16 = bf16(h @ W), el/er fused ----------------
#define LA_STRIDE 264

__global__ __launch_bounds__(256) void gemm_z_k(
    const float* __restrict__ h, const unsigned short* __restrict__ w16s,
    const float* __restrict__ a,
    unsigned short* __restrict__ z16, float* __restrict__ el, float* __restrict__ er)
{
    __shared__ unsigned short lA[64 * LA_STRIDE];
    const int t  = threadIdx.x;
    const int n0 = blockIdx.x * 64;

    #pragma unroll
    for (int p = 0; p < 16; ++p) {
        int f = p * 256 + t;
        int i = f >> 6;
        int col = (f & 63) * 4;
        float4 v = make_float4(0.f, 0.f, 0.f, 0.f);
        if (n0 + i < N_NODES)
            v = *(const float4*)&h[(size_t)(n0 + i) * IN_DIM + col];
        uint2 pk;
        pk.x = bf16rn(v.x) | (bf16rn(v.y) << 16);
        pk.y = bf16rn(v.z) | (bf16rn(v.w) << 16);
        *(uint2*)&lA[i * LA_STRIDE + col] = pk;
    }
    __syncthreads();

    const int w    = t >> 6;
    const int lane = t & 63;
    const int q    = lane >> 4;
    const int col  = lane & 15;

    f32x4 acc[8];
    #pragma unroll
    for (int c = 0; c < 8; ++c) acc[c] = (f32x4){0.f, 0.f, 0.f, 0.f};

    #pragma unroll
    for (int kc = 0; kc < 8; ++kc) {
        bf16x8 af = *(const bf16x8*)&lA[(w * 16 + col) * LA_STRIDE + kc * 32 + q * 8];
        bf16x8 bfr[8];
        #pragma unroll
        for (int c = 0; c < 8; ++c)
            bfr[c] = *(const bf16x8*)&w16s[((((kc * 8 + c) * 4 + q) * 16) + col) * 8];
        #pragma unroll
        for (int c = 0; c < 8; ++c)
            acc[c] = __builtin_amdgcn_mfma_f32_16x16x32_bf16(af, bfr[c], acc[c], 0, 0, 0);
    }

    float aL[8], aR[8];
    #pragma unroll
    for (int c = 0; c < 8; ++c) {
        aL[c] = a[c * 16 + col];
        aR[c] = a[128 + c * 16 + col];
    }
    #pragma unroll
    for (int r = 0; r < 4; ++r) {
        int node = n0 + w * 16 + q * 4 + r;
        float sl = 0.f, sr = 0.f;
        #pragma unroll
        for (int c = 0; c < 8; ++c) {
            sl += acc[c][r] * aL[c];
            sr += acc[c][r] * aR[c];
        }
        #pragma unroll
        for (int o = 1; o < 16; o <<= 1) {
            sl += __shfl_xor(sl, o, 64);
            sr += __shfl_xor(sr, o, 64);
        }
        if (node < N_NODES) {
            #pragma unroll
            for (int c = 0; c < 8; ++c)
                z16[(size_t)node * OUT_DIM + c * 16 + col] =
                    (unsigned short)bf16rn(acc[c][r]);
            if (col == 0) { el[node] = sl; er[node] = sr; }
        }
    }
}

// ---------------- phase 1: partition edges into dst-buckets ----------------
// ebuf entry: [e:32][src:17][localdst:9]
__global__ __launch_bounds__(256) void partition_k(
    const int* __restrict__ src, const int* __restrict__ dst,
    const float* __restrict__ el, const float* __restrict__ er,
    int* __restrict__ bucket_cursor, unsigned long long* __restrict__ ebuf)
{
    __shared__ int hist[NBUCK];
    __shared__ int gbaseL[NBUCK];
    const int t = threadIdx.x;
    for (int i = t; i < NBUCK; i += 256) hist[i] = 0;
    __syncthreads();

    const int e0 = blockIdx.x * EPB;
    int bucks[16], ranks[16];
    unsigned long long pk[16];
    #pragma unroll
    for (int k = 0; k < 16; ++k) {
        int e = e0 + k * 256 + t;
        bucks[k] = -1;
        if (e < N_EDGES) {
            int s = src[e], d = dst[e];
            float v = el[s] + er[d];
            v = (v > 0.0f) ? v : 0.01f * v;   // leaky_relu slope 0.01
            int b = d >> BSHIFT;
            bucks[k] = b;
            ranks[k] = atomicAdd(&hist[b], 1);
            pk[k] = ((unsigned long long)__float_as_uint(v) << 32)
                  | ((unsigned)s << BSHIFT) | (unsigned)(d & (BNODES - 1));
        }
    }
    __syncthreads();
    for (int i = t; i < NBUCK; i += 256)
        gbaseL[i] = atomicAdd(&bucket_cursor[i], hist[i]);
    __syncthreads();
    #pragma unroll
    for (int k = 0; k < 16; ++k)
        if (bucks[k] >= 0)
            ebuf[(size_t)bucks[k] * BCAP + gbaseL[bucks[k]] + ranks[k]] = pk[k];
}

// ---------------- phase 2: per-bucket fine sort + beg/end/emax ----------------
__global__ __launch_bounds__(256) void bucket_k(
    const int* __restrict__ bucket_cursor, const unsigned long long* __restrict__ ebuf,
    unsigned long long* __restrict__ perm, int* __restrict__ begA,
    int* __restrict__ endA, unsigned* __restrict__ emaxA)
{
    __shared__ int deg[BNODES];
    __shared__ int off[BNODES];
    __shared__ int cur[BNODES];
    __shared__ unsigned emaxL[BNODES];
    __shared__ int ssum[256];

    const int b = blockIdx.x;
    const int t = threadIdx.x;
    const int cnt = bucket_cursor[b];
    const unsigned long long* eb = ebuf + (size_t)b * BCAP;
    unsigned long long* pb = perm + (size_t)b * BCAP;

    for (int i = t; i < BNODES; i += 256) { deg[i] = 0; emaxL[i] = ENC_NEG_INF; }
    __syncthreads();

    // pass A: per-node degree histogram
    for (int i = t; i < cnt; i += 256)
        atomicAdd(&deg[(int)(eb[i] & (BNODES - 1))], 1);
    __syncthreads();

    // exclusive scan of padded degrees (512 elems, 2 per thread)
    int d0 = deg[2 * t], d1 = deg[2 * t + 1];
    int p0 = (d0 + 3) & ~3, p1 = (d1 + 3) & ~3;
    ssum[t] = p0 + p1;
    __syncthreads();
    for (int o = 1; o < 256; o <<= 1) {
        int v = (t >= o) ? ssum[t - o] : 0;
        __syncthreads();
        ssum[t] += v;
        __syncthreads();
    }
    int excl = ssum[t] - (p0 + p1);
    off[2 * t] = excl;       cur[2 * t] = excl;
    off[2 * t + 1] = excl + p0; cur[2 * t + 1] = excl + p0;
    __syncthreads();

    // pass B: place edges within bucket region, LDS emax
    for (int i = t; i < cnt; i += 256) {
        unsigned long long pv = eb[i];
        int ld = (int)(pv & (BNODES - 1));
        unsigned s  = (unsigned)((pv >> BSHIFT) & 0x1FFFFu);
        unsigned eb32 = (unsigned)(pv >> 32);
        int p = atomicAdd(&cur[ld], 1);
        pb[p] = ((unsigned long long)eb32 << 32) | s;
        unsigned enc = (eb32 & 0x80000000u) ? ~eb32 : (eb32 | 0x80000000u);
        atomicMax(&emaxL[ld], enc);
    }
    __syncthreads();

    // pad fill + dense beg/end/emax writes
    for (int i = t; i < BNODES; i += 256) {
        int n = b * BNODES + i;
        if (n < N_NODES) {
            int d  = deg[i];
            int pd = (d + 3) & ~3;
            int o  = off[i];
            int gb = b * BCAP + o;
            begA[n]  = gb;
            endA[n]  = gb + pd;
            emaxA[n] = emaxL[i];
            for (int j = o + d; j < o + pd; ++j) pb[j] = PAD_PAIR;
        }
    }
}

// ---------------- fused softmax + weighted gather ----------------
__global__ __launch_bounds__(256) void node_pass_k(
    const int* __restrict__ begA, const int* __restrict__ endA,
    const unsigned* __restrict__ emaxA, const unsigned long long* __restrict__ perm,
    const unsigned* __restrict__ z16, float* __restrict__ out)
{
    int n    = (blockIdx.x * blockDim.x + threadIdx.x) >> 6;
    int lane = threadIdx.x & 63;
    if (n >= N_NODES) return;
    int beg = begA[n], end = endA[n];

    float acc0 = 0.0f, acc1 = 0.0f;
    if (end > beg) {
        unsigned u = emaxA[n];
        float mx = (u & 0x80000000u) ? __uint_as_float(u ^ 0x80000000u)
                                     : __uint_as_float(~u);
        float denom = 0.0f;
        const uint4* pp = (const uint4*)perm;   // {src0,e0,src1,e1}
        #pragma unroll 2
        for (int i = (beg >> 2); i < (end >> 2); ++i) {
            uint4 pA = pp[2 * i];
            uint4 pB = pp[2 * i + 1];
            unsigned q0 = z16[(size_t)pA.x * 64 + lane];
            unsigned q1 = z16[(size_t)pA.z * 64 + lane];
            unsigned q2 = z16[(size_t)pB.x * 64 + lane];
            unsigned q3 = z16[(size_t)pB.z * 64 + lane];
            float w0 = __expf(__uint_as_float(pA.y) - mx);
            float w1 = __expf(__uint_as_float(pA.w) - mx);
            float w2 = __expf(__uint_as_float(pB.y) - mx);
            float w3 = __expf(__uint_as_float(pB.w) - mx);
            denom += (w0 + w1) + (w2 + w3);
            acc0 += w0 * __uint_as_float(q0 << 16)
                  + w1 * __uint_as_float(q1 << 16)
                  + w2 * __uint_as_float(q2 << 16)
                  + w3 * __uint_as_float(q3 << 16);
            acc1 += w0 * __uint_as_float(q0 & 0xFFFF0000u)
                  + w1 * __uint_as_float(q1 & 0xFFFF0000u)
                  + w2 * __uint_as_float(q2 & 0xFFFF0000u)
                  + w3 * __uint_as_float(q3 & 0xFFFF0000u);
        }
        float inv = 1.0f / denom;
        acc0 *= inv; acc1 *= inv;
    }
    *(float2*)&out[(size_t)n * OUT_DIM + lane * 2] = make_float2(acc0, acc1);
}

// ---------------- launch ----------------
extern "C" void kernel_launch(void* const* d_in, const int* in_sizes, int n_in,
                              void* d_out, int out_size, void* d_ws, size_t ws_size,
                              hipStream_t stream)
{
    (void)in_sizes; (void)n_in; (void)out_size; (void)ws_size;
    const float* h = (const float*)d_in[0];
    const float* W = (const float*)d_in[1];
    const float* a = (const float*)d_in[2];
    const int* src = (const int*)d_in[3];
    const int* dst = (const int*)d_in[4];
    float* out = (float*)d_out;

    char* ws = (char*)d_ws;
    size_t off = 0;
    auto alloc = [&](size_t bytes) -> char* {
        char* p = ws + off;
        off += (bytes + 255) & ~(size_t)255;
        return p;
    };
    unsigned short* z16  = (unsigned short*)alloc((size_t)N_NODES * OUT_DIM * 2);
    unsigned short* w16s = (unsigned short*)alloc((size_t)IN_DIM * OUT_DIM * 2);
    float*    el        = (float*)   alloc((size_t)N_NODES * 4);
    float*    er        = (float*)   alloc((size_t)N_NODES * 4);
    int*      bucket_cursor = (int*) alloc((size_t)NBUCK * 4);
    unsigned long long* ebuf = (unsigned long long*)alloc((size_t)NBUCK * BCAP * 8);
    unsigned long long* perm = (unsigned long long*)alloc((size_t)NBUCK * BCAP * 8);
    int*      begA      = (int*)     alloc((size_t)N_NODES * 4);
    int*      endA      = (int*)     alloc((size_t)N_NODES * 4);
    unsigned* emaxA     = (unsigned*)alloc((size_t)N_NODES * 4);

    init_k<<<1, 256, 0, stream>>>(bucket_cursor);
    w16s_k<<<(IN_DIM * OUT_DIM + 255) / 256, 256, 0, stream>>>(W, w16s);
    gemm_z_k<<<(N_NODES + 63) / 64, 256, 0, stream>>>(h, w16s, a, z16, el, er);
    partition_k<<<(N_EDGES + EPB - 1) / EPB, 256, 0, stream>>>(src, dst, el, er,
                                                               bucket_cursor, ebuf);
    bucket_k<<<NBUCK, 256, 0, stream>>>(bucket_cursor, ebuf, perm, begA, endA, emaxA);
    node_pass_k<<<(N_NODES * 64 + 255) / 256, 256, 0, stream>>>(begA, endA, emaxA, perm,
                                                                (const unsigned*)z16, out);
}

// Round 6
// 308.014 us; speedup vs baseline: 1.9834x; 1.0057x over previous
//
#include <hip/hip_runtime.h>
#include <cstdint>
#include <cstddef>

#define N_NODES 100000
#define N_EDGES 1600000
#define IN_DIM  256
#define OUT_DIM 128

#define NBUCK  391       // ceil(N_NODES / 256)
#define BSHIFT 8
#define BNODES 256       // nodes per bucket
#define BCAP   5632      // slots per bucket (mean padded ~4476, >18 sigma headroom)
#define EPB    4096      // edges per partition block

#define ENC_NEG_INF 0x00800000u   // encode(-FLT_MAX)

typedef __attribute__((ext_vector_type(8))) short bf16x8;
typedef __attribute__((ext_vector_type(4))) float f32x4;

__device__ __forceinline__ unsigned bf16rn(float f) {
    unsigned u = __float_as_uint(f);
    return (u + 0x7FFFu + ((u >> 16) & 1u)) >> 16;
}

// ---------------- init: zero bucket cursors ----------------
__global__ void init_k(int* __restrict__ bucket_cursor)
{
    int i = blockIdx.x * blockDim.x + threadIdx.x;
    if (i < NBUCK) bucket_cursor[i] = 0;
}

// ---------------- W -> bf16, swizzled to B-fragment order ----------------
__global__ void w16s_k(const float* __restrict__ W, unsigned short* __restrict__ w16s)
{
    int t = blockIdx.x * blockDim.x + threadIdx.x;
    if (t >= IN_DIM * OUT_DIM) return;
    int j  = t & 7;
    int n  = (t >> 3) & 15;
    int q  = (t >> 7) & 3;
    int c  = (t >> 9) & 7;
    int kc = t >> 12;
    int k   = kc * 32 + q * 8 + j;
    int dim = c * 16 + n;
    w16s[t] = (unsigned short)bf16rn(W[k * OUT_DIM + dim]);
}

// ---------------- MFMA GEMM: z16 = bf16(h @ W), el/er fused ----------------
#define LA_STRIDE 264

__global__ __launch_bounds__(256) void gemm_z_k(
    const float* __restrict__ h, const unsigned short* __restrict__ w16s,
    const float* __restrict__ a,
    unsigned short* __restrict__ z16, float* __restrict__ el, float* __restrict__ er)
{
    __shared__ unsigned short lA[64 * LA_STRIDE];
    const int t  = threadIdx.x;
    const int n0 = blockIdx.x * 64;

    #pragma unroll
    for (int p = 0; p < 16; ++p) {
        int f = p * 256 + t;
        int i = f >> 6;
        int col = (f & 63) * 4;
        float4 v = make_float4(0.f, 0.f, 0.f, 0.f);
        if (n0 + i < N_NODES)
            v = *(const float4*)&h[(size_t)(n0 + i) * IN_DIM + col];
        uint2 pk;
        pk.x = bf16rn(v.x) | (bf16rn(v.y) << 16);
        pk.y = bf16rn(v.z) | (bf16rn(v.w) << 16);
        *(uint2*)&lA[i * LA_STRIDE + col] = pk;
    }
    __syncthreads();

    const int w    = t >> 6;
    const int lane = t & 63;
    const int q    = lane >> 4;
    const int col  = lane & 15;

    f32x4 acc[8];
    #pragma unroll
    for (int c = 0; c < 8; ++c) acc[c] = (f32x4){0.f, 0.f, 0.f, 0.f};

    #pragma unroll
    for (int kc = 0; kc < 8; ++kc) {
        bf16x8 af = *(const bf16x8*)&lA[(w * 16 + col) * LA_STRIDE + kc * 32 + q * 8];
        bf16x8 bfr[8];
        #pragma unroll
        for (int c = 0; c < 8; ++c)
            bfr[c] = *(const bf16x8*)&w16s[((((kc * 8 + c) * 4 + q) * 16) + col) * 8];
        #pragma unroll
        for (int c = 0; c < 8; ++c)
            acc[c] = __builtin_amdgcn_mfma_f32_16x16x32_bf16(af, bfr[c], acc[c], 0, 0, 0);
    }

    float aL[8], aR[8];
    #pragma unroll
    for (int c = 0; c < 8; ++c) {
        aL[c] = a[c * 16 + col];
        aR[c] = a[128 + c * 16 + col];
    }
    #pragma unroll
    for (int r = 0; r < 4; ++r) {
        int node = n0 + w * 16 + q * 4 + r;
        float sl = 0.f, sr = 0.f;
        #pragma unroll
        for (int c = 0; c < 8; ++c) {
            sl += acc[c][r] * aL[c];
            sr += acc[c][r] * aR[c];
        }
        #pragma unroll
        for (int o = 1; o < 16; o <<= 1) {
            sl += __shfl_xor(sl, o, 64);
            sr += __shfl_xor(sr, o, 64);
        }
        if (node < N_NODES) {
            #pragma unroll
            for (int c = 0; c < 8; ++c)
                z16[(size_t)node * OUT_DIM + c * 16 + col] =
                    (unsigned short)bf16rn(acc[c][r]);
            if (col == 0) { el[node] = sl; er[node] = sr; }
        }
    }
}

// ---------------- phase 1: partition edges into dst-buckets ----------------
// ebuf entry: [e:32][src:17][localdst:8]
__global__ __launch_bounds__(256) void partition_k(
    const int* __restrict__ src, const int* __restrict__ dst,
    const float* __restrict__ el, const float* __restrict__ er,
    int* __restrict__ bucket_cursor, unsigned long long* __restrict__ ebuf)
{
    __shared__ int hist[NBUCK];
    __shared__ int gbaseL[NBUCK];
    const int t = threadIdx.x;
    for (int i = t; i < NBUCK; i += 256) hist[i] = 0;
    __syncthreads();

    const int e0 = blockIdx.x * EPB;
    int bucks[16], ranks[16];
    unsigned long long pk[16];
    #pragma unroll
    for (int k = 0; k < 16; ++k) {
        int e = e0 + k * 256 + t;
        bucks[k] = -1;
        if (e < N_EDGES) {
            int s = src[e], d = dst[e];
            float v = el[s] + er[d];
            v = (v > 0.0f) ? v : 0.01f * v;   // leaky_relu slope 0.01
            int b = d >> BSHIFT;
            bucks[k] = b;
            ranks[k] = atomicAdd(&hist[b], 1);
            pk[k] = ((unsigned long long)__float_as_uint(v) << 32)
                  | ((unsigned)s << BSHIFT) | (unsigned)(d & (BNODES - 1));
        }
    }
    __syncthreads();
    for (int i = t; i < NBUCK; i += 256)
        gbaseL[i] = atomicAdd(&bucket_cursor[i], hist[i]);
    __syncthreads();
    #pragma unroll
    for (int k = 0; k < 16; ++k)
        if (bucks[k] >= 0)
            ebuf[(size_t)bucks[k] * BCAP + gbaseL[bucks[k]] + ranks[k]] = pk[k];
}

// ---------------- phase 2: per-bucket softmax + fine sort ----------------
// perm entry: [w:32][src:32] with w = exp(e - emax) already applied; pads w=0
__global__ __launch_bounds__(256) void bucket_k(
    const int* __restrict__ bucket_cursor, const unsigned long long* __restrict__ ebuf,
    unsigned long long* __restrict__ perm, int* __restrict__ begA,
    int* __restrict__ endA, float* __restrict__ denomA)
{
    __shared__ int deg[BNODES];
    __shared__ int off[BNODES];
    __shared__ int cur[BNODES];
    __shared__ unsigned emaxL[BNODES];
    __shared__ float denomL[BNODES];
    __shared__ int ssum[256];

    const int b = blockIdx.x;
    const int t = threadIdx.x;
    const int cnt = bucket_cursor[b];
    const unsigned long long* eb = ebuf + (size_t)b * BCAP;
    unsigned long long* pb = perm + (size_t)b * BCAP;

    deg[t] = 0; emaxL[t] = ENC_NEG_INF; denomL[t] = 0.0f;
    __syncthreads();

    // pass A: degree histogram + segment max
    for (int i = t; i < cnt; i += 256) {
        unsigned long long pv = eb[i];
        int ld = (int)(pv & (BNODES - 1));
        unsigned e32 = (unsigned)(pv >> 32);
        unsigned enc = (e32 & 0x80000000u) ? ~e32 : (e32 | 0x80000000u);
        atomicAdd(&deg[ld], 1);
        atomicMax(&emaxL[ld], enc);
    }
    __syncthreads();

    // exclusive scan of padded degrees (1 node/thread)
    int d  = deg[t];
    int pd = (d + 3) & ~3;
    ssum[t] = pd;
    __syncthreads();
    for (int o = 1; o < 256; o <<= 1) {
        int v = (t >= o) ? ssum[t - o] : 0;
        __syncthreads();
        ssum[t] += v;
        __syncthreads();
    }
    int excl = ssum[t] - pd;
    off[t] = excl; cur[t] = excl;
    __syncthreads();

    // pass B: w = exp(e - mx); denom accumulate; place (w,src)
    for (int i = t; i < cnt; i += 256) {
        unsigned long long pv = eb[i];
        int ld = (int)(pv & (BNODES - 1));
        unsigned s = (unsigned)((pv >> BSHIFT) & 0x1FFFFu);
        float e = __uint_as_float((unsigned)(pv >> 32));
        unsigned u = emaxL[ld];
        float mx = (u & 0x80000000u) ? __uint_as_float(u ^ 0x80000000u)
                                     : __uint_as_float(~u);
        float w = __expf(e - mx);
        atomicAdd(&denomL[ld], w);
        int p = atomicAdd(&cur[ld], 1);
        pb[p] = ((unsigned long long)__float_as_uint(w) << 32) | s;
    }
    __syncthreads();

    // pass C: dense per-node outputs + zero-weight pad fill
    int n = b * BNODES + t;
    if (n < N_NODES) {
        int o  = off[t];
        int gb = b * BCAP + o;
        begA[n]   = gb;
        endA[n]   = gb + pd;
        denomA[n] = denomL[t];
        for (int j = o + d; j < o + pd; ++j) pb[j] = 0ull;   // w=0, src=0
    }
}

// ---------------- weighted gather (softmax weights precomputed) ----------------
__global__ __launch_bounds__(256) void node_pass_k(
    const int* __restrict__ begA, const int* __restrict__ endA,
    const float* __restrict__ denomA, const unsigned long long* __restrict__ perm,
    const unsigned* __restrict__ z16, float* __restrict__ out)
{
    int n    = (blockIdx.x * blockDim.x + threadIdx.x) >> 6;
    int lane = threadIdx.x & 63;
    if (n >= N_NODES) return;
    int beg = begA[n], end = endA[n];

    float acc0 = 0.0f, acc1 = 0.0f;
    if (end > beg) {
        const uint4* pp = (const uint4*)perm;   // {src0,w0,src1,w1}
        #pragma unroll 2
        for (int i = (beg >> 2); i < (end >> 2); ++i) {
            uint4 pA = pp[2 * i];
            uint4 pB = pp[2 * i + 1];
            unsigned q0 = z16[(size_t)pA.x * 64 + lane];
            unsigned q1 = z16[(size_t)pA.z * 64 + lane];
            unsigned q2 = z16[(size_t)pB.x * 64 + lane];
            unsigned q3 = z16[(size_t)pB.z * 64 + lane];
            float w0 = __uint_as_float(pA.y);
            float w1 = __uint_as_float(pA.w);
            float w2 = __uint_as_float(pB.y);
            float w3 = __uint_as_float(pB.w);
            acc0 += w0 * __uint_as_float(q0 << 16)
                  + w1 * __uint_as_float(q1 << 16)
                  + w2 * __uint_as_float(q2 << 16)
                  + w3 * __uint_as_float(q3 << 16);
            acc1 += w0 * __uint_as_float(q0 & 0xFFFF0000u)
                  + w1 * __uint_as_float(q1 & 0xFFFF0000u)
                  + w2 * __uint_as_float(q2 & 0xFFFF0000u)
                  + w3 * __uint_as_float(q3 & 0xFFFF0000u);
        }
        float inv = 1.0f / denomA[n];
        acc0 *= inv; acc1 *= inv;
    }
    *(float2*)&out[(size_t)n * OUT_DIM + lane * 2] = make_float2(acc0, acc1);
}

// ---------------- launch ----------------
extern "C" void kernel_launch(void* const* d_in, const int* in_sizes, int n_in,
                              void* d_out, int out_size, void* d_ws, size_t ws_size,
                              hipStream_t stream)
{
    (void)in_sizes; (void)n_in; (void)out_size; (void)ws_size;
    const float* h = (const float*)d_in[0];
    const float* W = (const float*)d_in[1];
    const float* a = (const float*)d_in[2];
    const int* src = (const int*)d_in[3];
    const int* dst = (const int*)d_in[4];
    float* out = (float*)d_out;

    char* ws = (char*)d_ws;
    size_t off = 0;
    auto alloc = [&](size_t bytes) -> char* {
        char* p = ws + off;
        off += (bytes + 255) & ~(size_t)255;
        return p;
    };
    unsigned short* z16  = (unsigned short*)alloc((size_t)N_NODES * OUT_DIM * 2);
    unsigned short* w16s = (unsigned short*)alloc((size_t)IN_DIM * OUT_DIM * 2);
    float*    el        = (float*)   alloc((size_t)N_NODES * 4);
    float*    er        = (float*)   alloc((size_t)N_NODES * 4);
    int*      bucket_cursor = (int*) alloc((size_t)NBUCK * 4);
    unsigned long long* ebuf = (unsigned long long*)alloc((size_t)NBUCK * BCAP * 8);
    unsigned long long* perm = (unsigned long long*)alloc((size_t)NBUCK * BCAP * 8);
    int*      begA      = (int*)     alloc((size_t)N_NODES * 4);
    int*      endA      = (int*)     alloc((size_t)N_NODES * 4);
    float*    denomA    = (float*)   alloc((size_t)N_NODES * 4);

    init_k<<<(NBUCK + 255) / 256, 256, 0, stream>>>(bucket_cursor);
    w16s_k<<<(IN_DIM * OUT_DIM + 255) / 256, 256, 0, stream>>>(W, w16s);
    gemm_z_k<<<(N_NODES + 63) / 64, 256, 0, stream>>>(h, w16s, a, z16, el, er);
    partition_k<<<(N_EDGES + EPB - 1) / EPB, 256, 0, stream>>>(src, dst, el, er,
                                                               bucket_cursor, ebuf);
    bucket_k<<<NBUCK, 256, 0, stream>>>(bucket_cursor, ebuf, perm, begA, endA, denomA);
    node_pass_k<<<(N_NODES * 64 + 255) / 256, 256, 0, stream>>>(begA, endA, denomA, perm,
                                                                (const unsigned*)z16, out);
}